// Round 7
// baseline (102.208 us; speedup 1.0000x reference)
//
#include <hip/hip_runtime.h>
#include <hip/hip_fp16.h>

// Perspective3d: voxels [4,32,64,64,64] f32 -> out [4,32,48,96,96] f32.
//
// Round 7: barrier-free sample kernel (round-6 design; fixed the
// __builtin_nontemporal_* compile error by using clang ext_vector_type
// instead of HIP_vector_type float4). All LDS producer/consumer pairs are
// intra-wave (per-wave offset/weight tables, per-wave transpose tile), so no
// __syncthreads at all -- waves overlap gather/compute/store freely.
// f32x4 output stores (8 lanes = one 128B channel row). Transpose pre-pass
// unchanged except nontemporal f32 voxel loads (don't evict voxt from L2).

typedef float f32x4 __attribute__((ext_vector_type(4)));

static constexpr int Bn = 4, Cn = 32, DV = 64, HV = 64, WV = 64;
static constexpr int ZS = 48, XY = 96;
static constexpr int SP = ZS * XY * XY;            // 442368 spatial / batch
static constexpr long long VOXCH = (long long)DV * HV * WV;  // 262144
static constexpr size_t WS_NEED = (size_t)Bn * VOXCH * Cn * sizeof(__half); // 67 MB

static __device__ __forceinline__ unsigned pk2h(float a, float b) {
    __half2 h2;
    h2.x = __float2half(a);
    h2.y = __float2half(b);
    return *reinterpret_cast<unsigned*>(&h2);
}

// ---------------- pre-pass: [B,C,DHW] f32 -> [B,DHW,C] f16 ----------------
__global__ __launch_bounds__(256) void transpose_cl(
    const float* __restrict__ vox, __half* __restrict__ voxt)
{
    __shared__ float tile[32][65];
    const int nt = (int)(VOXCH / 64);          // 4096 tiles per batch
    const int blk = blockIdx.x;
    const int b  = blk / nt;
    const int v0 = (blk - b * nt) * 64;
    const int t  = threadIdx.x;
    {
        const int c = t >> 3;                  // 0..31
        const int i = (t & 7) * 8;             // 0..56
        const float* src = vox + ((size_t)(b * Cn + c)) * VOXCH + v0 + i;
        const f32x4 a0 = __builtin_nontemporal_load((const f32x4*)src);
        const f32x4 a1 = __builtin_nontemporal_load((const f32x4*)(src + 4));
        tile[c][i + 0] = a0.x; tile[c][i + 1] = a0.y;
        tile[c][i + 2] = a0.z; tile[c][i + 3] = a0.w;
        tile[c][i + 4] = a1.x; tile[c][i + 5] = a1.y;
        tile[c][i + 6] = a1.z; tile[c][i + 7] = a1.w;
    }
    __syncthreads();
    {
        const int v  = t >> 2;                 // 0..63
        const int c8 = (t & 3) * 8;            // 0,8,16,24
        const unsigned p0 = pk2h(tile[c8 + 0][v], tile[c8 + 1][v]);
        const unsigned p1 = pk2h(tile[c8 + 2][v], tile[c8 + 3][v]);
        const unsigned p2 = pk2h(tile[c8 + 4][v], tile[c8 + 5][v]);
        const unsigned p3 = pk2h(tile[c8 + 6][v], tile[c8 + 7][v]);
        __half* dst = voxt + ((size_t)b * VOXCH + v0 + v) * Cn + c8;
        *(uint4*)dst = make_uint4(p0, p1, p2, p3);
    }
}

// ---------------- main: barrier-free phase-split fp16 sample ----------------
static constexpr int NBLK2 = Bn * ZS * XY;     // 18432 blocks (one (b,z,h) row)
static constexpr int CH2   = NBLK2 / 8;        // 2304 per XCD

__global__ __launch_bounds__(192) void sample_cl(
    const __half* __restrict__ voxt,
    const float* __restrict__ rot,
    const float* __restrict__ tran,
    const float* __restrict__ sc,
    const float* __restrict__ det,
    float* __restrict__ out)
{
    __shared__ __align__(16) int   soff[3][32][8];   // per-wave corner byte offs
    __shared__ __align__(16) float swt[3][32][8];    // per-wave combined weights
    __shared__ __align__(16) float tr2[3][32][36];   // per-wave [c][w] out tile

    // bijective XCD-chunk swizzle (18432 % 8 == 0)
    const int logical = (blockIdx.x % 8) * CH2 + blockIdx.x / 8;
    const int b   = logical / (ZS * XY);
    const int rem = logical - b * (ZS * XY);
    const int z   = rem / XY;
    const int h   = rem - z * XY;

    const int t    = threadIdx.x;
    const int wave = t >> 6;                   // 0..2 -> w-tile of 32
    const int lane = t & 63;
    const int w0   = wave * 32;

    // ---- phase 1 (per-wave): lanes 0..31 compute one sample each ----
    if (lane < 32) {
        const int w = w0 + lane;
        const float* R  = rot  + b * 16;
        const float* T  = tran + b * 3;
        const float* S  = sc   + b * 3;
        const float* DT = det  + b * 2;
        const float t0 = T[0], t1 = T[1], t2 = T[2];

        float M[3][4];
#pragma unroll
        for (int i2 = 0; i2 < 3; ++i2) {
            const float inv = 1.0f / S[i2];
            const float m0 = R[0 * 4 + i2], m1 = R[1 * 4 + i2], m2 = R[2 * 4 + i2];
            M[i2][0] = inv * m0;
            M[i2][1] = inv * m1;
            M[i2][2] = inv * m2;
            M[i2][3] = -inv * (m0 * t0 + m1 * t1 + m2 * t2);
        }

        const float STEP = 96.0f / 95.0f;
        const float Zt = -0.5f + z * (1.0f / 47.0f) + t2;
        const float Xt = (w * STEP - 48.0f + DT[0]) * Zt * 0.01f;
        const float Yt = (h * STEP - 48.0f + DT[1]) * Zt * 0.01f;

        const float gx = 2.0f * (M[0][0] * Xt + M[0][1] * Yt + M[0][2] * Zt + M[0][3]);
        const float gy = 2.0f * (M[1][0] * Xt + M[1][1] * Yt + M[1][2] * Zt + M[1][3]);
        const float gz = 2.0f * (M[2][0] * Xt + M[2][1] * Yt + M[2][2] * Zt + M[2][3]);

        const float ix = (gx + 1.0f) * 31.5f;
        const float iy = (gy + 1.0f) * 31.5f;
        const float iz = (gz + 1.0f) * 31.5f;

        const float fxf = floorf(ix), fyf = floorf(iy), fzf = floorf(iz);
        const float fx = ix - fxf, fy = iy - fyf, fz = iz - fzf;
        const int x0 = (int)fxf, y0 = (int)fyf, z0 = (int)fzf;

        const float ax0 = (1.0f - fx) * ((x0 >= 0     && x0 < WV)     ? 1.0f : 0.0f);
        const float ax1 = fx          * ((x0 + 1 >= 0 && x0 + 1 < WV) ? 1.0f : 0.0f);
        const float ay0 = (1.0f - fy) * ((y0 >= 0     && y0 < HV)     ? 1.0f : 0.0f);
        const float ay1 = fy          * ((y0 + 1 >= 0 && y0 + 1 < HV) ? 1.0f : 0.0f);
        const float az0 = (1.0f - fz) * ((z0 >= 0     && z0 < DV)     ? 1.0f : 0.0f);
        const float az1 = fz          * ((z0 + 1 >= 0 && z0 + 1 < DV) ? 1.0f : 0.0f);

        const int xc0 = min(max(x0, 0), WV - 1), xc1 = min(max(x0 + 1, 0), WV - 1);
        const int yc0 = min(max(y0, 0), HV - 1), yc1 = min(max(y0 + 1, 0), HV - 1);
        const int zc0 = min(max(z0, 0), DV - 1), zc1 = min(max(z0 + 1, 0), DV - 1);

        const int r00 = (zc0 * HV + yc0) * WV;
        const int r01 = (zc0 * HV + yc1) * WV;
        const int r10 = (zc1 * HV + yc0) * WV;
        const int r11 = (zc1 * HV + yc1) * WV;

        // byte offsets into f16 channels-last volume (voxel stride = 64 B)
        soff[wave][lane][0] = (r00 + xc0) << 6;
        soff[wave][lane][1] = (r00 + xc1) << 6;
        soff[wave][lane][2] = (r01 + xc0) << 6;
        soff[wave][lane][3] = (r01 + xc1) << 6;
        soff[wave][lane][4] = (r10 + xc0) << 6;
        soff[wave][lane][5] = (r10 + xc1) << 6;
        soff[wave][lane][6] = (r11 + xc0) << 6;
        soff[wave][lane][7] = (r11 + xc1) << 6;

        const float wz0y0 = az0 * ay0, wz0y1 = az0 * ay1;
        const float wz1y0 = az1 * ay0, wz1y1 = az1 * ay1;
        swt[wave][lane][0] = wz0y0 * ax0;
        swt[wave][lane][1] = wz0y0 * ax1;
        swt[wave][lane][2] = wz0y1 * ax0;
        swt[wave][lane][3] = wz0y1 * ax1;
        swt[wave][lane][4] = wz1y0 * ax0;
        swt[wave][lane][5] = wz1y0 * ax1;
        swt[wave][lane][6] = wz1y1 * ax0;
        swt[wave][lane][7] = wz1y1 * ax1;
    }
    // no barrier: producers and consumers are the same wave (wave-synchronous)

    // ---- phase 2: gather. 16 lanes per sample, 2 channels per lane ----
    const int sg = lane >> 4;                  // sample-in-quad 0..3
    const int li = lane & 15;                  // channel-pair index
    const int lb = li * 4;                     // byte offset within 64B corner

    const char* vb = (const char*)voxt + (size_t)b * VOXCH * (Cn * 2);

#pragma unroll 4
    for (int i = 0; i < 8; ++i) {
        const int sl = 4 * i + sg;             // sample within wave (0..31)
        const int4   o0 = *(const int4*)(&soff[wave][sl][0]);
        const int4   o1 = *(const int4*)(&soff[wave][sl][4]);
        const float4 wa = *(const float4*)(&swt[wave][sl][0]);
        const float4 wb = *(const float4*)(&swt[wave][sl][4]);

        const float2 f0 = __half22float2(*(const __half2*)(vb + (o0.x + lb)));
        const float2 f1 = __half22float2(*(const __half2*)(vb + (o0.y + lb)));
        const float2 f2 = __half22float2(*(const __half2*)(vb + (o0.z + lb)));
        const float2 f3 = __half22float2(*(const __half2*)(vb + (o0.w + lb)));
        const float2 f4 = __half22float2(*(const __half2*)(vb + (o1.x + lb)));
        const float2 f5 = __half22float2(*(const __half2*)(vb + (o1.y + lb)));
        const float2 f6 = __half22float2(*(const __half2*)(vb + (o1.z + lb)));
        const float2 f7 = __half22float2(*(const __half2*)(vb + (o1.w + lb)));

        float acc0 = wa.x * f0.x;
        float acc1 = wa.x * f0.y;
        acc0 = fmaf(wa.y, f1.x, acc0); acc1 = fmaf(wa.y, f1.y, acc1);
        acc0 = fmaf(wa.z, f2.x, acc0); acc1 = fmaf(wa.z, f2.y, acc1);
        acc0 = fmaf(wa.w, f3.x, acc0); acc1 = fmaf(wa.w, f3.y, acc1);
        acc0 = fmaf(wb.x, f4.x, acc0); acc1 = fmaf(wb.x, f4.y, acc1);
        acc0 = fmaf(wb.y, f5.x, acc0); acc1 = fmaf(wb.y, f5.y, acc1);
        acc0 = fmaf(wb.z, f6.x, acc0); acc1 = fmaf(wb.z, f6.y, acc1);
        acc0 = fmaf(wb.w, f7.x, acc0); acc1 = fmaf(wb.w, f7.y, acc1);

        tr2[wave][2 * li + 0][sl] = acc0;      // [c][w] tile, intra-wave only
        tr2[wave][2 * li + 1][sl] = acc1;
    }
    // no barrier: tr2[wave] read below by the same wave

    // ---- store: 8 lanes = one 128B channel row, f32x4 each ----
    const size_t orow = (size_t)b * Cn * SP + (size_t)(z * XY + h) * XY + w0;
    const int cb = lane >> 3;                  // channel within octet
    const int w4 = (lane & 7) * 4;             // w-quad
#pragma unroll
    for (int c2 = 0; c2 < 4; ++c2) {
        const int cc = c2 * 8 + cb;
        const f32x4 v = *(const f32x4*)(&tr2[wave][cc][w4]);
        __builtin_nontemporal_store(v, (f32x4*)(out + orow + (size_t)cc * SP + w4));
    }
}

// ---------------- fallback (round-2 kernel) if ws too small ----------------
static constexpr int TW = 32, TH = 4, TZ = 2;
static constexpr int NBW = XY / TW, NBH = XY / TH, NBZ = ZS / TZ;
static constexpr int BLOCKS_PER_B = NBW * NBH * NBZ;
static constexpr int NBLOCKS = Bn * BLOCKS_PER_B;
static constexpr int CHUNK = NBLOCKS / 8;

__global__ __launch_bounds__(256) void persp3d_fallback(
    const float* __restrict__ vox, const float* __restrict__ rot,
    const float* __restrict__ tran, const float* __restrict__ sc,
    const float* __restrict__ det, float* __restrict__ out)
{
    const int xcd = blockIdx.x % 8;
    const int logical = xcd * CHUNK + blockIdx.x / 8;
    const int b = logical / BLOCKS_PER_B;
    int rem = logical - b * BLOCKS_PER_B;
    const int bz = rem / (NBH * NBW);
    rem -= bz * (NBH * NBW);
    const int bh = rem / NBW;
    const int bw = rem - bh * NBW;
    const int t = threadIdx.x;
    const int w = bw * TW + (t & (TW - 1));
    const int h = bh * TH + ((t >> 5) & (TH - 1));
    const int z = bz * TZ + (t >> 7);
    const int sp = (z * XY + h) * XY + w;

    const float* R = rot + b * 16;
    const float* T = tran + b * 3;
    const float* S = sc + b * 3;
    const float* DT = det + b * 2;
    const float t0 = T[0], t1 = T[1], t2 = T[2];
    float M[3][4];
#pragma unroll
    for (int i = 0; i < 3; ++i) {
        const float inv = 1.0f / S[i];
        const float m0 = R[0 * 4 + i], m1 = R[1 * 4 + i], m2 = R[2 * 4 + i];
        M[i][0] = inv * m0; M[i][1] = inv * m1; M[i][2] = inv * m2;
        M[i][3] = -inv * (m0 * t0 + m1 * t1 + m2 * t2);
    }
    const float STEP = 96.0f / 95.0f;
    const float Zt = -0.5f + z * (1.0f / 47.0f) + t2;
    const float Xt = (w * STEP - 48.0f + DT[0]) * Zt * 0.01f;
    const float Yt = (h * STEP - 48.0f + DT[1]) * Zt * 0.01f;
    const float gx = 2.0f * (M[0][0] * Xt + M[0][1] * Yt + M[0][2] * Zt + M[0][3]);
    const float gy = 2.0f * (M[1][0] * Xt + M[1][1] * Yt + M[1][2] * Zt + M[1][3]);
    const float gz = 2.0f * (M[2][0] * Xt + M[2][1] * Yt + M[2][2] * Zt + M[2][3]);
    const float ix = (gx + 1.0f) * 31.5f, iy = (gy + 1.0f) * 31.5f, iz = (gz + 1.0f) * 31.5f;
    const float fx0 = floorf(ix), fy0 = floorf(iy), fz0 = floorf(iz);
    const float fx = ix - fx0, fy = iy - fy0, fz = iz - fz0;
    const int x0 = (int)fx0, y0 = (int)fy0, z0 = (int)fz0;
    const float ax0 = (1.0f - fx) * ((x0 >= 0 && x0 < WV) ? 1.0f : 0.0f);
    const float ax1 = fx * ((x0 + 1 >= 0 && x0 + 1 < WV) ? 1.0f : 0.0f);
    const float ay0 = (1.0f - fy) * ((y0 >= 0 && y0 < HV) ? 1.0f : 0.0f);
    const float ay1 = fy * ((y0 + 1 >= 0 && y0 + 1 < HV) ? 1.0f : 0.0f);
    const float az0 = (1.0f - fz) * ((z0 >= 0 && z0 < DV) ? 1.0f : 0.0f);
    const float az1 = fz * ((z0 + 1 >= 0 && z0 + 1 < DV) ? 1.0f : 0.0f);
    const int xc0 = min(max(x0, 0), WV - 1), xc1 = min(max(x0 + 1, 0), WV - 1);
    const int yc0 = min(max(y0, 0), HV - 1), yc1 = min(max(y0 + 1, 0), HV - 1);
    const int zc0 = min(max(z0, 0), DV - 1), zc1 = min(max(z0 + 1, 0), DV - 1);
    const int o000 = (zc0 * HV + yc0) * WV + xc0, o001 = (zc0 * HV + yc0) * WV + xc1;
    const int o010 = (zc0 * HV + yc1) * WV + xc0, o011 = (zc0 * HV + yc1) * WV + xc1;
    const int o100 = (zc1 * HV + yc0) * WV + xc0, o101 = (zc1 * HV + yc0) * WV + xc1;
    const int o110 = (zc1 * HV + yc1) * WV + xc0, o111 = (zc1 * HV + yc1) * WV + xc1;
    const float* p = vox + (size_t)b * Cn * VOXCH;
    float* op = out + (size_t)b * Cn * SP + sp;
#pragma unroll 8
    for (int cc = 0; cc < Cn; ++cc) {
        const float v000 = p[o000], v001 = p[o001];
        const float v010 = p[o010], v011 = p[o011];
        const float v100 = p[o100], v101 = p[o101];
        const float v110 = p[o110], v111 = p[o111];
        const float q00 = ax0 * v000 + ax1 * v001;
        const float q01 = ax0 * v010 + ax1 * v011;
        const float q10 = ax0 * v100 + ax1 * v101;
        const float q11 = ax0 * v110 + ax1 * v111;
        const float r0 = ay0 * q00 + ay1 * q01;
        const float r1 = ay0 * q10 + ay1 * q11;
        __builtin_nontemporal_store(az0 * r0 + az1 * r1, op);
        p += VOXCH; op += SP;
    }
}

extern "C" void kernel_launch(void* const* d_in, const int* in_sizes, int n_in,
                              void* d_out, int out_size, void* d_ws, size_t ws_size,
                              hipStream_t stream) {
    const float* vox  = (const float*)d_in[0];
    const float* rot  = (const float*)d_in[1];
    const float* tran = (const float*)d_in[2];
    const float* sc   = (const float*)d_in[3];
    const float* det  = (const float*)d_in[4];
    float* out = (float*)d_out;

    if (ws_size >= WS_NEED) {
        __half* voxt = (__half*)d_ws;
        transpose_cl<<<dim3(Bn * (int)(VOXCH / 64)), dim3(256), 0, stream>>>(vox, voxt);
        sample_cl<<<dim3(NBLK2), dim3(192), 0, stream>>>(voxt, rot, tran, sc, det, out);
    } else {
        persp3d_fallback<<<dim3(NBLOCKS), dim3(256), 0, stream>>>(vox, rot, tran, sc, det, out);
    }
}

// Round 8
// 92.113 us; speedup vs baseline: 1.1096x; 1.1096x over previous
//
#include <hip/hip_runtime.h>
#include <hip/hip_fp16.h>

// Perspective3d: voxels [4,32,64,64,64] f32 -> out [4,32,48,96,96] f32.
//
// Round 8: R5 base (90us known-good: plain transpose loads, [w][c] tr tile,
// float2 LDS writes, dword NT stores) + barrier-free dataflow only:
// phase 1 is per-wave (lanes 0..31 compute the wave's 32 samples into
// per-wave soff/swt), tr tile was already per-wave -> zero __syncthreads.
// Phase-2 loop fully unrolled for outstanding-load MLP.

static constexpr int Bn = 4, Cn = 32, DV = 64, HV = 64, WV = 64;
static constexpr int ZS = 48, XY = 96;
static constexpr int SP = ZS * XY * XY;            // 442368 spatial / batch
static constexpr long long VOXCH = (long long)DV * HV * WV;  // 262144
static constexpr size_t WS_NEED = (size_t)Bn * VOXCH * Cn * sizeof(__half); // 67 MB

static __device__ __forceinline__ unsigned pk2h(float a, float b) {
    __half2 h2;
    h2.x = __float2half(a);
    h2.y = __float2half(b);
    return *reinterpret_cast<unsigned*>(&h2);
}

// ---------------- pre-pass: [B,C,DHW] f32 -> [B,DHW,C] f16 ----------------
__global__ __launch_bounds__(256) void transpose_cl(
    const float* __restrict__ vox, __half* __restrict__ voxt)
{
    __shared__ float tile[32][65];
    const int nt = (int)(VOXCH / 64);          // 4096 tiles per batch
    const int blk = blockIdx.x;
    const int b  = blk / nt;
    const int v0 = (blk - b * nt) * 64;
    const int t  = threadIdx.x;
    {
        const int c = t >> 3;                  // 0..31
        const int i = (t & 7) * 8;             // 0..56
        const float* src = vox + ((size_t)(b * Cn + c)) * VOXCH + v0 + i;
        const float4 a0 = *(const float4*)src;
        const float4 a1 = *(const float4*)(src + 4);
        tile[c][i + 0] = a0.x; tile[c][i + 1] = a0.y;
        tile[c][i + 2] = a0.z; tile[c][i + 3] = a0.w;
        tile[c][i + 4] = a1.x; tile[c][i + 5] = a1.y;
        tile[c][i + 6] = a1.z; tile[c][i + 7] = a1.w;
    }
    __syncthreads();
    {
        const int v  = t >> 2;                 // 0..63
        const int c8 = (t & 3) * 8;            // 0,8,16,24
        const unsigned p0 = pk2h(tile[c8 + 0][v], tile[c8 + 1][v]);
        const unsigned p1 = pk2h(tile[c8 + 2][v], tile[c8 + 3][v]);
        const unsigned p2 = pk2h(tile[c8 + 4][v], tile[c8 + 5][v]);
        const unsigned p3 = pk2h(tile[c8 + 6][v], tile[c8 + 7][v]);
        __half* dst = voxt + ((size_t)b * VOXCH + v0 + v) * Cn + c8;
        *(uint4*)dst = make_uint4(p0, p1, p2, p3);
    }
}

// ---------------- main: barrier-free phase-split fp16 sample ----------------
static constexpr int NBLK2 = Bn * ZS * XY;     // 18432 blocks (one (b,z,h) row)
static constexpr int CH2   = NBLK2 / 8;        // 2304 per XCD

__global__ __launch_bounds__(192) void sample_cl(
    const __half* __restrict__ voxt,
    const float* __restrict__ rot,
    const float* __restrict__ tran,
    const float* __restrict__ sc,
    const float* __restrict__ det,
    float* __restrict__ out)
{
    __shared__ __align__(16) int   soff[3][32][8];   // per-wave corner byte offs
    __shared__ __align__(16) float swt[3][32][8];    // per-wave combined weights
    __shared__ float tr[3][32][34];                  // per-wave [w][c] out tile

    // bijective XCD-chunk swizzle (18432 % 8 == 0)
    const int logical = (blockIdx.x % 8) * CH2 + blockIdx.x / 8;
    const int b   = logical / (ZS * XY);
    const int rem = logical - b * (ZS * XY);
    const int z   = rem / XY;
    const int h   = rem - z * XY;

    const int t    = threadIdx.x;
    const int wave = t >> 6;                   // 0..2 -> w-tile of 32
    const int lane = t & 63;
    const int w0   = wave * 32;

    // ---- phase 1 (per-wave): lanes 0..31 compute one sample each ----
    if (lane < 32) {
        const int w = w0 + lane;
        const float* R  = rot  + b * 16;
        const float* T  = tran + b * 3;
        const float* S  = sc   + b * 3;
        const float* DT = det  + b * 2;
        const float t0 = T[0], t1 = T[1], t2 = T[2];

        float M[3][4];
#pragma unroll
        for (int i2 = 0; i2 < 3; ++i2) {
            const float inv = 1.0f / S[i2];
            const float m0 = R[0 * 4 + i2], m1 = R[1 * 4 + i2], m2 = R[2 * 4 + i2];
            M[i2][0] = inv * m0;
            M[i2][1] = inv * m1;
            M[i2][2] = inv * m2;
            M[i2][3] = -inv * (m0 * t0 + m1 * t1 + m2 * t2);
        }

        const float STEP = 96.0f / 95.0f;
        const float Zt = -0.5f + z * (1.0f / 47.0f) + t2;
        const float Xt = (w * STEP - 48.0f + DT[0]) * Zt * 0.01f;
        const float Yt = (h * STEP - 48.0f + DT[1]) * Zt * 0.01f;

        const float gx = 2.0f * (M[0][0] * Xt + M[0][1] * Yt + M[0][2] * Zt + M[0][3]);
        const float gy = 2.0f * (M[1][0] * Xt + M[1][1] * Yt + M[1][2] * Zt + M[1][3]);
        const float gz = 2.0f * (M[2][0] * Xt + M[2][1] * Yt + M[2][2] * Zt + M[2][3]);

        const float ix = (gx + 1.0f) * 31.5f;
        const float iy = (gy + 1.0f) * 31.5f;
        const float iz = (gz + 1.0f) * 31.5f;

        const float fxf = floorf(ix), fyf = floorf(iy), fzf = floorf(iz);
        const float fx = ix - fxf, fy = iy - fyf, fz = iz - fzf;
        const int x0 = (int)fxf, y0 = (int)fyf, z0 = (int)fzf;

        const float ax0 = (1.0f - fx) * ((x0 >= 0     && x0 < WV)     ? 1.0f : 0.0f);
        const float ax1 = fx          * ((x0 + 1 >= 0 && x0 + 1 < WV) ? 1.0f : 0.0f);
        const float ay0 = (1.0f - fy) * ((y0 >= 0     && y0 < HV)     ? 1.0f : 0.0f);
        const float ay1 = fy          * ((y0 + 1 >= 0 && y0 + 1 < HV) ? 1.0f : 0.0f);
        const float az0 = (1.0f - fz) * ((z0 >= 0     && z0 < DV)     ? 1.0f : 0.0f);
        const float az1 = fz          * ((z0 + 1 >= 0 && z0 + 1 < DV) ? 1.0f : 0.0f);

        const int xc0 = min(max(x0, 0), WV - 1), xc1 = min(max(x0 + 1, 0), WV - 1);
        const int yc0 = min(max(y0, 0), HV - 1), yc1 = min(max(y0 + 1, 0), HV - 1);
        const int zc0 = min(max(z0, 0), DV - 1), zc1 = min(max(z0 + 1, 0), DV - 1);

        const int r00 = (zc0 * HV + yc0) * WV;
        const int r01 = (zc0 * HV + yc1) * WV;
        const int r10 = (zc1 * HV + yc0) * WV;
        const int r11 = (zc1 * HV + yc1) * WV;

        // byte offsets into f16 channels-last volume (voxel stride = 64 B)
        soff[wave][lane][0] = (r00 + xc0) << 6;
        soff[wave][lane][1] = (r00 + xc1) << 6;
        soff[wave][lane][2] = (r01 + xc0) << 6;
        soff[wave][lane][3] = (r01 + xc1) << 6;
        soff[wave][lane][4] = (r10 + xc0) << 6;
        soff[wave][lane][5] = (r10 + xc1) << 6;
        soff[wave][lane][6] = (r11 + xc0) << 6;
        soff[wave][lane][7] = (r11 + xc1) << 6;

        const float wz0y0 = az0 * ay0, wz0y1 = az0 * ay1;
        const float wz1y0 = az1 * ay0, wz1y1 = az1 * ay1;
        swt[wave][lane][0] = wz0y0 * ax0;
        swt[wave][lane][1] = wz0y0 * ax1;
        swt[wave][lane][2] = wz0y1 * ax0;
        swt[wave][lane][3] = wz0y1 * ax1;
        swt[wave][lane][4] = wz1y0 * ax0;
        swt[wave][lane][5] = wz1y0 * ax1;
        swt[wave][lane][6] = wz1y1 * ax0;
        swt[wave][lane][7] = wz1y1 * ax1;
    }
    // no barrier: soff/swt[wave] produced and consumed by the same wave

    // ---- phase 2: gather. 16 lanes per sample, 2 channels per lane ----
    const int sg = lane >> 4;                  // sample-in-quad 0..3
    const int li = lane & 15;                  // channel-pair index
    const int lb = li * 4;                     // byte offset within 64B corner

    const char* vb = (const char*)voxt + (size_t)b * VOXCH * (Cn * 2);

#pragma unroll
    for (int i = 0; i < 8; ++i) {
        const int sl = 4 * i + sg;             // sample within wave (0..31)
        const int4   o0 = *(const int4*)(&soff[wave][sl][0]);
        const int4   o1 = *(const int4*)(&soff[wave][sl][4]);
        const float4 wa = *(const float4*)(&swt[wave][sl][0]);
        const float4 wb = *(const float4*)(&swt[wave][sl][4]);

        const float2 f0 = __half22float2(*(const __half2*)(vb + (o0.x + lb)));
        const float2 f1 = __half22float2(*(const __half2*)(vb + (o0.y + lb)));
        const float2 f2 = __half22float2(*(const __half2*)(vb + (o0.z + lb)));
        const float2 f3 = __half22float2(*(const __half2*)(vb + (o0.w + lb)));
        const float2 f4 = __half22float2(*(const __half2*)(vb + (o1.x + lb)));
        const float2 f5 = __half22float2(*(const __half2*)(vb + (o1.y + lb)));
        const float2 f6 = __half22float2(*(const __half2*)(vb + (o1.z + lb)));
        const float2 f7 = __half22float2(*(const __half2*)(vb + (o1.w + lb)));

        float acc0 = wa.x * f0.x;
        float acc1 = wa.x * f0.y;
        acc0 = fmaf(wa.y, f1.x, acc0); acc1 = fmaf(wa.y, f1.y, acc1);
        acc0 = fmaf(wa.z, f2.x, acc0); acc1 = fmaf(wa.z, f2.y, acc1);
        acc0 = fmaf(wa.w, f3.x, acc0); acc1 = fmaf(wa.w, f3.y, acc1);
        acc0 = fmaf(wb.x, f4.x, acc0); acc1 = fmaf(wb.x, f4.y, acc1);
        acc0 = fmaf(wb.y, f5.x, acc0); acc1 = fmaf(wb.y, f5.y, acc1);
        acc0 = fmaf(wb.z, f6.x, acc0); acc1 = fmaf(wb.z, f6.y, acc1);
        acc0 = fmaf(wb.w, f7.x, acc0); acc1 = fmaf(wb.w, f7.y, acc1);

        *(float2*)(&tr[wave][sl][li * 2]) = make_float2(acc0, acc1);
    }
    // no barrier: tr[wave] read below by the same wave

    // ---- store: lanes -> consecutive w, coalesced rows per channel ----
    const size_t obase = (size_t)b * Cn * SP + (size_t)(z * XY + h) * XY + w0;
    const int p  = lane >> 5;
    const int wl = lane & 31;
#pragma unroll
    for (int c2 = 0; c2 < 16; ++c2) {
        const int cc = 2 * c2 + p;
        __builtin_nontemporal_store(tr[wave][wl][cc],
                                    out + obase + (size_t)cc * SP + wl);
    }
}

// ---------------- fallback (round-2 kernel) if ws too small ----------------
static constexpr int TW = 32, TH = 4, TZ = 2;
static constexpr int NBW = XY / TW, NBH = XY / TH, NBZ = ZS / TZ;
static constexpr int BLOCKS_PER_B = NBW * NBH * NBZ;
static constexpr int NBLOCKS = Bn * BLOCKS_PER_B;
static constexpr int CHUNK = NBLOCKS / 8;

__global__ __launch_bounds__(256) void persp3d_fallback(
    const float* __restrict__ vox, const float* __restrict__ rot,
    const float* __restrict__ tran, const float* __restrict__ sc,
    const float* __restrict__ det, float* __restrict__ out)
{
    const int xcd = blockIdx.x % 8;
    const int logical = xcd * CHUNK + blockIdx.x / 8;
    const int b = logical / BLOCKS_PER_B;
    int rem = logical - b * BLOCKS_PER_B;
    const int bz = rem / (NBH * NBW);
    rem -= bz * (NBH * NBW);
    const int bh = rem / NBW;
    const int bw = rem - bh * NBW;
    const int t = threadIdx.x;
    const int w = bw * TW + (t & (TW - 1));
    const int h = bh * TH + ((t >> 5) & (TH - 1));
    const int z = bz * TZ + (t >> 7);
    const int sp = (z * XY + h) * XY + w;

    const float* R = rot + b * 16;
    const float* T = tran + b * 3;
    const float* S = sc + b * 3;
    const float* DT = det + b * 2;
    const float t0 = T[0], t1 = T[1], t2 = T[2];
    float M[3][4];
#pragma unroll
    for (int i = 0; i < 3; ++i) {
        const float inv = 1.0f / S[i];
        const float m0 = R[0 * 4 + i], m1 = R[1 * 4 + i], m2 = R[2 * 4 + i];
        M[i][0] = inv * m0; M[i][1] = inv * m1; M[i][2] = inv * m2;
        M[i][3] = -inv * (m0 * t0 + m1 * t1 + m2 * t2);
    }
    const float STEP = 96.0f / 95.0f;
    const float Zt = -0.5f + z * (1.0f / 47.0f) + t2;
    const float Xt = (w * STEP - 48.0f + DT[0]) * Zt * 0.01f;
    const float Yt = (h * STEP - 48.0f + DT[1]) * Zt * 0.01f;
    const float gx = 2.0f * (M[0][0] * Xt + M[0][1] * Yt + M[0][2] * Zt + M[0][3]);
    const float gy = 2.0f * (M[1][0] * Xt + M[1][1] * Yt + M[1][2] * Zt + M[1][3]);
    const float gz = 2.0f * (M[2][0] * Xt + M[2][1] * Yt + M[2][2] * Zt + M[2][3]);
    const float ix = (gx + 1.0f) * 31.5f, iy = (gy + 1.0f) * 31.5f, iz = (gz + 1.0f) * 31.5f;
    const float fx0 = floorf(ix), fy0 = floorf(iy), fz0 = floorf(iz);
    const float fx = ix - fx0, fy = iy - fy0, fz = iz - fz0;
    const int x0 = (int)fx0, y0 = (int)fy0, z0 = (int)fz0;
    const float ax0 = (1.0f - fx) * ((x0 >= 0 && x0 < WV) ? 1.0f : 0.0f);
    const float ax1 = fx * ((x0 + 1 >= 0 && x0 + 1 < WV) ? 1.0f : 0.0f);
    const float ay0 = (1.0f - fy) * ((y0 >= 0 && y0 < HV) ? 1.0f : 0.0f);
    const float ay1 = fy * ((y0 + 1 >= 0 && y0 + 1 < HV) ? 1.0f : 0.0f);
    const float az0 = (1.0f - fz) * ((z0 >= 0 && z0 < DV) ? 1.0f : 0.0f);
    const float az1 = fz * ((z0 + 1 >= 0 && z0 + 1 < DV) ? 1.0f : 0.0f);
    const int xc0 = min(max(x0, 0), WV - 1), xc1 = min(max(x0 + 1, 0), WV - 1);
    const int yc0 = min(max(y0, 0), HV - 1), yc1 = min(max(y0 + 1, 0), HV - 1);
    const int zc0 = min(max(z0, 0), DV - 1), zc1 = min(max(z0 + 1, 0), DV - 1);
    const int o000 = (zc0 * HV + yc0) * WV + xc0, o001 = (zc0 * HV + yc0) * WV + xc1;
    const int o010 = (zc0 * HV + yc1) * WV + xc0, o011 = (zc0 * HV + yc1) * WV + xc1;
    const int o100 = (zc1 * HV + yc0) * WV + xc0, o101 = (zc1 * HV + yc0) * WV + xc1;
    const int o110 = (zc1 * HV + yc1) * WV + xc0, o111 = (zc1 * HV + yc1) * WV + xc1;
    const float* p = vox + (size_t)b * Cn * VOXCH;
    float* op = out + (size_t)b * Cn * SP + sp;
#pragma unroll 8
    for (int cc = 0; cc < Cn; ++cc) {
        const float v000 = p[o000], v001 = p[o001];
        const float v010 = p[o010], v011 = p[o011];
        const float v100 = p[o100], v101 = p[o101];
        const float v110 = p[o110], v111 = p[o111];
        const float q00 = ax0 * v000 + ax1 * v001;
        const float q01 = ax0 * v010 + ax1 * v011;
        const float q10 = ax0 * v100 + ax1 * v101;
        const float q11 = ax0 * v110 + ax1 * v111;
        const float r0 = ay0 * q00 + ay1 * q01;
        const float r1 = ay0 * q10 + ay1 * q11;
        __builtin_nontemporal_store(az0 * r0 + az1 * r1, op);
        p += VOXCH; op += SP;
    }
}

extern "C" void kernel_launch(void* const* d_in, const int* in_sizes, int n_in,
                              void* d_out, int out_size, void* d_ws, size_t ws_size,
                              hipStream_t stream) {
    const float* vox  = (const float*)d_in[0];
    const float* rot  = (const float*)d_in[1];
    const float* tran = (const float*)d_in[2];
    const float* sc   = (const float*)d_in[3];
    const float* det  = (const float*)d_in[4];
    float* out = (float*)d_out;

    if (ws_size >= WS_NEED) {
        __half* voxt = (__half*)d_ws;
        transpose_cl<<<dim3(Bn * (int)(VOXCH / 64)), dim3(256), 0, stream>>>(vox, voxt);
        sample_cl<<<dim3(NBLK2), dim3(192), 0, stream>>>(voxt, rot, tran, sc, det, out);
    } else {
        persp3d_fallback<<<dim3(NBLOCKS), dim3(256), 0, stream>>>(vox, rot, tran, sc, det, out);
    }
}

// Round 9
// 90.638 us; speedup vs baseline: 1.1277x; 1.0163x over previous
//
#include <hip/hip_runtime.h>
#include <hip/hip_fp16.h>

// Perspective3d: voxels [4,32,64,64,64] f32 -> out [4,32,48,96,96] f32.
//
// Round 9: R8 base + per-batch coefficient hoisting. setup_coefs (1 tiny
// block) computes, per batch: ix/iy/iz = (A0*u + A1*v + A2)*Zt + A3 with
// u = w*(STEP/100)+U0, v = h*(STEP/100)+V0, Zt = z/47+Z0. Sample phase 1
// drops from ~90 VALU ops (3 IEEE divides, matrix assembly) to ~30.
// Rest unchanged: f16 channels-last transpose, 16-lane/sample gather,
// per-wave LDS dataflow (no barriers), NT dword stores.

static constexpr int Bn = 4, Cn = 32, DV = 64, HV = 64, WV = 64;
static constexpr int ZS = 48, XY = 96;
static constexpr int SP = ZS * XY * XY;            // 442368 spatial / batch
static constexpr long long VOXCH = (long long)DV * HV * WV;  // 262144
static constexpr size_t VOXT_BYTES = (size_t)Bn * VOXCH * Cn * sizeof(__half); // 67.1 MB
static constexpr size_t WS_NEED = VOXT_BYTES + Bn * 16 * sizeof(float);

static __device__ __forceinline__ unsigned pk2h(float a, float b) {
    __half2 h2;
    h2.x = __float2half(a);
    h2.y = __float2half(b);
    return *reinterpret_cast<unsigned*>(&h2);
}

// ---------------- setup: per-batch affine coefficients ----------------
__global__ __launch_bounds__(64) void setup_coefs(
    const float* __restrict__ rot,
    const float* __restrict__ tran,
    const float* __restrict__ sc,
    const float* __restrict__ det,
    float* __restrict__ coef)
{
    const int b = threadIdx.x;
    if (b >= Bn) return;
    const float* R  = rot  + b * 16;
    const float* T  = tran + b * 3;
    const float* S  = sc   + b * 3;
    const float* DT = det  + b * 2;
    const float t0 = T[0], t1 = T[1], t2 = T[2];

    float* C = coef + b * 16;
#pragma unroll
    for (int i = 0; i < 3; ++i) {
        const float inv = 1.0f / S[i];
        const float m0 = R[0 * 4 + i], m1 = R[1 * 4 + i], m2 = R[2 * 4 + i];
        // M[i][k] = inv*R[k][i]; M[i][3] = -inv*(R·t)
        C[i * 4 + 0] = 63.0f * (inv * m0);
        C[i * 4 + 1] = 63.0f * (inv * m1);
        C[i * 4 + 2] = 63.0f * (inv * m2);
        C[i * 4 + 3] = 63.0f * (-inv * (m0 * t0 + m1 * t1 + m2 * t2)) + 31.5f;
    }
    C[12] = (DT[0] - 48.0f) * 0.01f;   // U0
    C[13] = (DT[1] - 48.0f) * 0.01f;   // V0
    C[14] = t2 - 0.5f;                 // Z0
    C[15] = 0.0f;
}

// ---------------- pre-pass: [B,C,DHW] f32 -> [B,DHW,C] f16 ----------------
__global__ __launch_bounds__(256) void transpose_cl(
    const float* __restrict__ vox, __half* __restrict__ voxt)
{
    __shared__ float tile[32][65];
    const int nt = (int)(VOXCH / 64);          // 4096 tiles per batch
    const int blk = blockIdx.x;
    const int b  = blk / nt;
    const int v0 = (blk - b * nt) * 64;
    const int t  = threadIdx.x;
    {
        const int c = t >> 3;                  // 0..31
        const int i = (t & 7) * 8;             // 0..56
        const float* src = vox + ((size_t)(b * Cn + c)) * VOXCH + v0 + i;
        const float4 a0 = *(const float4*)src;
        const float4 a1 = *(const float4*)(src + 4);
        tile[c][i + 0] = a0.x; tile[c][i + 1] = a0.y;
        tile[c][i + 2] = a0.z; tile[c][i + 3] = a0.w;
        tile[c][i + 4] = a1.x; tile[c][i + 5] = a1.y;
        tile[c][i + 6] = a1.z; tile[c][i + 7] = a1.w;
    }
    __syncthreads();
    {
        const int v  = t >> 2;                 // 0..63
        const int c8 = (t & 3) * 8;            // 0,8,16,24
        const unsigned p0 = pk2h(tile[c8 + 0][v], tile[c8 + 1][v]);
        const unsigned p1 = pk2h(tile[c8 + 2][v], tile[c8 + 3][v]);
        const unsigned p2 = pk2h(tile[c8 + 4][v], tile[c8 + 5][v]);
        const unsigned p3 = pk2h(tile[c8 + 6][v], tile[c8 + 7][v]);
        __half* dst = voxt + ((size_t)b * VOXCH + v0 + v) * Cn + c8;
        *(uint4*)dst = make_uint4(p0, p1, p2, p3);
    }
}

// ---------------- main: barrier-free phase-split fp16 sample ----------------
static constexpr int NBLK2 = Bn * ZS * XY;     // 18432 blocks (one (b,z,h) row)
static constexpr int CH2   = NBLK2 / 8;        // 2304 per XCD

__global__ __launch_bounds__(192) void sample_cl(
    const __half* __restrict__ voxt,
    const float* __restrict__ coef,
    float* __restrict__ out)
{
    __shared__ __align__(16) int   soff[3][32][8];   // per-wave corner byte offs
    __shared__ __align__(16) float swt[3][32][8];    // per-wave combined weights
    __shared__ float tr[3][32][34];                  // per-wave [w][c] out tile

    // bijective XCD-chunk swizzle (18432 % 8 == 0)
    const int logical = (blockIdx.x % 8) * CH2 + blockIdx.x / 8;
    const int b   = logical / (ZS * XY);
    const int rem = logical - b * (ZS * XY);
    const int z   = rem / XY;
    const int h   = rem - z * XY;

    const int t    = threadIdx.x;
    const int wave = t >> 6;                   // 0..2 -> w-tile of 32
    const int lane = t & 63;
    const int w0   = wave * 32;

    const float* C = coef + b * 16;            // uniform -> scalar loads

    // ---- phase 1 (per-wave): lanes 0..31 compute one sample each ----
    if (lane < 32) {
        const int w = w0 + lane;
        const float S100 = (96.0f / 95.0f) * 0.01f;
        const float u  = fmaf((float)w, S100, C[12]);
        const float v  = fmaf((float)h, S100, C[13]);
        const float Zt = fmaf((float)z, 1.0f / 47.0f, C[14]);

        const float ix = fmaf(fmaf(C[0], u, fmaf(C[1], v, C[2])), Zt, C[3]);
        const float iy = fmaf(fmaf(C[4], u, fmaf(C[5], v, C[6])), Zt, C[7]);
        const float iz = fmaf(fmaf(C[8], u, fmaf(C[9], v, C[10])), Zt, C[11]);

        const float fxf = floorf(ix), fyf = floorf(iy), fzf = floorf(iz);
        const float fx = ix - fxf, fy = iy - fyf, fz = iz - fzf;
        const int x0 = (int)fxf, y0 = (int)fyf, z0 = (int)fzf;

        const float ax0 = (1.0f - fx) * ((x0 >= 0     && x0 < WV)     ? 1.0f : 0.0f);
        const float ax1 = fx          * ((x0 + 1 >= 0 && x0 + 1 < WV) ? 1.0f : 0.0f);
        const float ay0 = (1.0f - fy) * ((y0 >= 0     && y0 < HV)     ? 1.0f : 0.0f);
        const float ay1 = fy          * ((y0 + 1 >= 0 && y0 + 1 < HV) ? 1.0f : 0.0f);
        const float az0 = (1.0f - fz) * ((z0 >= 0     && z0 < DV)     ? 1.0f : 0.0f);
        const float az1 = fz          * ((z0 + 1 >= 0 && z0 + 1 < DV) ? 1.0f : 0.0f);

        const int xc0 = min(max(x0, 0), WV - 1), xc1 = min(max(x0 + 1, 0), WV - 1);
        const int yc0 = min(max(y0, 0), HV - 1), yc1 = min(max(y0 + 1, 0), HV - 1);
        const int zc0 = min(max(z0, 0), DV - 1), zc1 = min(max(z0 + 1, 0), DV - 1);

        const int r00 = (zc0 * HV + yc0) * WV;
        const int r01 = (zc0 * HV + yc1) * WV;
        const int r10 = (zc1 * HV + yc0) * WV;
        const int r11 = (zc1 * HV + yc1) * WV;

        // byte offsets into f16 channels-last volume (voxel stride = 64 B)
        soff[wave][lane][0] = (r00 + xc0) << 6;
        soff[wave][lane][1] = (r00 + xc1) << 6;
        soff[wave][lane][2] = (r01 + xc0) << 6;
        soff[wave][lane][3] = (r01 + xc1) << 6;
        soff[wave][lane][4] = (r10 + xc0) << 6;
        soff[wave][lane][5] = (r10 + xc1) << 6;
        soff[wave][lane][6] = (r11 + xc0) << 6;
        soff[wave][lane][7] = (r11 + xc1) << 6;

        const float wz0y0 = az0 * ay0, wz0y1 = az0 * ay1;
        const float wz1y0 = az1 * ay0, wz1y1 = az1 * ay1;
        swt[wave][lane][0] = wz0y0 * ax0;
        swt[wave][lane][1] = wz0y0 * ax1;
        swt[wave][lane][2] = wz0y1 * ax0;
        swt[wave][lane][3] = wz0y1 * ax1;
        swt[wave][lane][4] = wz1y0 * ax0;
        swt[wave][lane][5] = wz1y0 * ax1;
        swt[wave][lane][6] = wz1y1 * ax0;
        swt[wave][lane][7] = wz1y1 * ax1;
    }
    // no barrier: soff/swt[wave] produced and consumed by the same wave

    // ---- phase 2: gather. 16 lanes per sample, 2 channels per lane ----
    const int sg = lane >> 4;                  // sample-in-quad 0..3
    const int li = lane & 15;                  // channel-pair index
    const int lb = li * 4;                     // byte offset within 64B corner

    const char* vb = (const char*)voxt + (size_t)b * VOXCH * (Cn * 2);

#pragma unroll
    for (int i = 0; i < 8; ++i) {
        const int sl = 4 * i + sg;             // sample within wave (0..31)
        const int4   o0 = *(const int4*)(&soff[wave][sl][0]);
        const int4   o1 = *(const int4*)(&soff[wave][sl][4]);
        const float4 wa = *(const float4*)(&swt[wave][sl][0]);
        const float4 wb = *(const float4*)(&swt[wave][sl][4]);

        const float2 f0 = __half22float2(*(const __half2*)(vb + (o0.x + lb)));
        const float2 f1 = __half22float2(*(const __half2*)(vb + (o0.y + lb)));
        const float2 f2 = __half22float2(*(const __half2*)(vb + (o0.z + lb)));
        const float2 f3 = __half22float2(*(const __half2*)(vb + (o0.w + lb)));
        const float2 f4 = __half22float2(*(const __half2*)(vb + (o1.x + lb)));
        const float2 f5 = __half22float2(*(const __half2*)(vb + (o1.y + lb)));
        const float2 f6 = __half22float2(*(const __half2*)(vb + (o1.z + lb)));
        const float2 f7 = __half22float2(*(const __half2*)(vb + (o1.w + lb)));

        float acc0 = wa.x * f0.x;
        float acc1 = wa.x * f0.y;
        acc0 = fmaf(wa.y, f1.x, acc0); acc1 = fmaf(wa.y, f1.y, acc1);
        acc0 = fmaf(wa.z, f2.x, acc0); acc1 = fmaf(wa.z, f2.y, acc1);
        acc0 = fmaf(wa.w, f3.x, acc0); acc1 = fmaf(wa.w, f3.y, acc1);
        acc0 = fmaf(wb.x, f4.x, acc0); acc1 = fmaf(wb.x, f4.y, acc1);
        acc0 = fmaf(wb.y, f5.x, acc0); acc1 = fmaf(wb.y, f5.y, acc1);
        acc0 = fmaf(wb.z, f6.x, acc0); acc1 = fmaf(wb.z, f6.y, acc1);
        acc0 = fmaf(wb.w, f7.x, acc0); acc1 = fmaf(wb.w, f7.y, acc1);

        *(float2*)(&tr[wave][sl][li * 2]) = make_float2(acc0, acc1);
    }
    // no barrier: tr[wave] read below by the same wave

    // ---- store: lanes -> consecutive w, coalesced rows per channel ----
    const size_t obase = (size_t)b * Cn * SP + (size_t)(z * XY + h) * XY + w0;
    const int p  = lane >> 5;
    const int wl = lane & 31;
#pragma unroll
    for (int c2 = 0; c2 < 16; ++c2) {
        const int cc = 2 * c2 + p;
        __builtin_nontemporal_store(tr[wave][wl][cc],
                                    out + obase + (size_t)cc * SP + wl);
    }
}

// ---------------- fallback (round-2 kernel) if ws too small ----------------
static constexpr int TW = 32, TH = 4, TZ = 2;
static constexpr int NBW = XY / TW, NBH = XY / TH, NBZ = ZS / TZ;
static constexpr int BLOCKS_PER_B = NBW * NBH * NBZ;
static constexpr int NBLOCKS = Bn * BLOCKS_PER_B;
static constexpr int CHUNK = NBLOCKS / 8;

__global__ __launch_bounds__(256) void persp3d_fallback(
    const float* __restrict__ vox, const float* __restrict__ rot,
    const float* __restrict__ tran, const float* __restrict__ sc,
    const float* __restrict__ det, float* __restrict__ out)
{
    const int xcd = blockIdx.x % 8;
    const int logical = xcd * CHUNK + blockIdx.x / 8;
    const int b = logical / BLOCKS_PER_B;
    int rem = logical - b * BLOCKS_PER_B;
    const int bz = rem / (NBH * NBW);
    rem -= bz * (NBH * NBW);
    const int bh = rem / NBW;
    const int bw = rem - bh * NBW;
    const int t = threadIdx.x;
    const int w = bw * TW + (t & (TW - 1));
    const int h = bh * TH + ((t >> 5) & (TH - 1));
    const int z = bz * TZ + (t >> 7);
    const int sp = (z * XY + h) * XY + w;

    const float* R = rot + b * 16;
    const float* T = tran + b * 3;
    const float* S = sc + b * 3;
    const float* DT = det + b * 2;
    const float t0 = T[0], t1 = T[1], t2 = T[2];
    float M[3][4];
#pragma unroll
    for (int i = 0; i < 3; ++i) {
        const float inv = 1.0f / S[i];
        const float m0 = R[0 * 4 + i], m1 = R[1 * 4 + i], m2 = R[2 * 4 + i];
        M[i][0] = inv * m0; M[i][1] = inv * m1; M[i][2] = inv * m2;
        M[i][3] = -inv * (m0 * t0 + m1 * t1 + m2 * t2);
    }
    const float STEP = 96.0f / 95.0f;
    const float Zt = -0.5f + z * (1.0f / 47.0f) + t2;
    const float Xt = (w * STEP - 48.0f + DT[0]) * Zt * 0.01f;
    const float Yt = (h * STEP - 48.0f + DT[1]) * Zt * 0.01f;
    const float gx = 2.0f * (M[0][0] * Xt + M[0][1] * Yt + M[0][2] * Zt + M[0][3]);
    const float gy = 2.0f * (M[1][0] * Xt + M[1][1] * Yt + M[1][2] * Zt + M[1][3]);
    const float gz = 2.0f * (M[2][0] * Xt + M[2][1] * Yt + M[2][2] * Zt + M[2][3]);
    const float ix = (gx + 1.0f) * 31.5f, iy = (gy + 1.0f) * 31.5f, iz = (gz + 1.0f) * 31.5f;
    const float fx0 = floorf(ix), fy0 = floorf(iy), fz0 = floorf(iz);
    const float fx = ix - fx0, fy = iy - fy0, fz = iz - fz0;
    const int x0 = (int)fx0, y0 = (int)fy0, z0 = (int)fz0;
    const float ax0 = (1.0f - fx) * ((x0 >= 0 && x0 < WV) ? 1.0f : 0.0f);
    const float ax1 = fx * ((x0 + 1 >= 0 && x0 + 1 < WV) ? 1.0f : 0.0f);
    const float ay0 = (1.0f - fy) * ((y0 >= 0 && y0 < HV) ? 1.0f : 0.0f);
    const float ay1 = fy * ((y0 + 1 >= 0 && y0 + 1 < HV) ? 1.0f : 0.0f);
    const float az0 = (1.0f - fz) * ((z0 >= 0 && z0 < DV) ? 1.0f : 0.0f);
    const float az1 = fz * ((z0 + 1 >= 0 && z0 + 1 < DV) ? 1.0f : 0.0f);
    const int xc0 = min(max(x0, 0), WV - 1), xc1 = min(max(x0 + 1, 0), WV - 1);
    const int yc0 = min(max(y0, 0), HV - 1), yc1 = min(max(y0 + 1, 0), HV - 1);
    const int zc0 = min(max(z0, 0), DV - 1), zc1 = min(max(z0 + 1, 0), DV - 1);
    const int o000 = (zc0 * HV + yc0) * WV + xc0, o001 = (zc0 * HV + yc0) * WV + xc1;
    const int o010 = (zc0 * HV + yc1) * WV + xc0, o011 = (zc0 * HV + yc1) * WV + xc1;
    const int o100 = (zc1 * HV + yc0) * WV + xc0, o101 = (zc1 * HV + yc0) * WV + xc1;
    const int o110 = (zc1 * HV + yc1) * WV + xc0, o111 = (zc1 * HV + yc1) * WV + xc1;
    const float* p = vox + (size_t)b * Cn * VOXCH;
    float* op = out + (size_t)b * Cn * SP + sp;
#pragma unroll 8
    for (int cc = 0; cc < Cn; ++cc) {
        const float v000 = p[o000], v001 = p[o001];
        const float v010 = p[o010], v011 = p[o011];
        const float v100 = p[o100], v101 = p[o101];
        const float v110 = p[o110], v111 = p[o111];
        const float q00 = ax0 * v000 + ax1 * v001;
        const float q01 = ax0 * v010 + ax1 * v011;
        const float q10 = ax0 * v100 + ax1 * v101;
        const float q11 = ax0 * v110 + ax1 * v111;
        const float r0 = ay0 * q00 + ay1 * q01;
        const float r1 = ay0 * q10 + ay1 * q11;
        __builtin_nontemporal_store(az0 * r0 + az1 * r1, op);
        p += VOXCH; op += SP;
    }
}

extern "C" void kernel_launch(void* const* d_in, const int* in_sizes, int n_in,
                              void* d_out, int out_size, void* d_ws, size_t ws_size,
                              hipStream_t stream) {
    const float* vox  = (const float*)d_in[0];
    const float* rot  = (const float*)d_in[1];
    const float* tran = (const float*)d_in[2];
    const float* sc   = (const float*)d_in[3];
    const float* det  = (const float*)d_in[4];
    float* out = (float*)d_out;

    if (ws_size >= WS_NEED) {
        __half* voxt = (__half*)d_ws;
        float* coef  = (float*)((char*)d_ws + VOXT_BYTES);
        setup_coefs<<<dim3(1), dim3(64), 0, stream>>>(rot, tran, sc, det, coef);
        transpose_cl<<<dim3(Bn * (int)(VOXCH / 64)), dim3(256), 0, stream>>>(vox, voxt);
        sample_cl<<<dim3(NBLK2), dim3(192), 0, stream>>>(voxt, coef, out);
    } else {
        persp3d_fallback<<<dim3(NBLOCKS), dim3(256), 0, stream>>>(vox, rot, tran, sc, det, out);
    }
}

// Round 10
// 88.894 us; speedup vs baseline: 1.1498x; 1.0196x over previous
//
#include <hip/hip_runtime.h>
#include <hip/hip_fp16.h>

// Perspective3d: voxels [4,32,64,64,64] f32 -> out [4,32,48,96,96] f32.
//
// Round 10: R9 + ONE change: f32x4 nontemporal output stores (4 instrs/lane
// instead of 16). LDS [w][c] tile unchanged; the 16 stride-34 dword reads per
// lane are 2-way bank-aliased (free on 32-bank LDS with wave64). Everything
// else identical to R9 (setup_coefs hoisting, f16 channels-last transpose,
// 16-lane/sample gather, per-wave barrier-free LDS dataflow).

typedef float f32x4 __attribute__((ext_vector_type(4)));

static constexpr int Bn = 4, Cn = 32, DV = 64, HV = 64, WV = 64;
static constexpr int ZS = 48, XY = 96;
static constexpr int SP = ZS * XY * XY;            // 442368 spatial / batch
static constexpr long long VOXCH = (long long)DV * HV * WV;  // 262144
static constexpr size_t VOXT_BYTES = (size_t)Bn * VOXCH * Cn * sizeof(__half); // 67.1 MB
static constexpr size_t WS_NEED = VOXT_BYTES + Bn * 16 * sizeof(float);

static __device__ __forceinline__ unsigned pk2h(float a, float b) {
    __half2 h2;
    h2.x = __float2half(a);
    h2.y = __float2half(b);
    return *reinterpret_cast<unsigned*>(&h2);
}

// ---------------- setup: per-batch affine coefficients ----------------
__global__ __launch_bounds__(64) void setup_coefs(
    const float* __restrict__ rot,
    const float* __restrict__ tran,
    const float* __restrict__ sc,
    const float* __restrict__ det,
    float* __restrict__ coef)
{
    const int b = threadIdx.x;
    if (b >= Bn) return;
    const float* R  = rot  + b * 16;
    const float* T  = tran + b * 3;
    const float* S  = sc   + b * 3;
    const float* DT = det  + b * 2;
    const float t0 = T[0], t1 = T[1], t2 = T[2];

    float* C = coef + b * 16;
#pragma unroll
    for (int i = 0; i < 3; ++i) {
        const float inv = 1.0f / S[i];
        const float m0 = R[0 * 4 + i], m1 = R[1 * 4 + i], m2 = R[2 * 4 + i];
        C[i * 4 + 0] = 63.0f * (inv * m0);
        C[i * 4 + 1] = 63.0f * (inv * m1);
        C[i * 4 + 2] = 63.0f * (inv * m2);
        C[i * 4 + 3] = 63.0f * (-inv * (m0 * t0 + m1 * t1 + m2 * t2)) + 31.5f;
    }
    C[12] = (DT[0] - 48.0f) * 0.01f;   // U0
    C[13] = (DT[1] - 48.0f) * 0.01f;   // V0
    C[14] = t2 - 0.5f;                 // Z0
    C[15] = 0.0f;
}

// ---------------- pre-pass: [B,C,DHW] f32 -> [B,DHW,C] f16 ----------------
__global__ __launch_bounds__(256) void transpose_cl(
    const float* __restrict__ vox, __half* __restrict__ voxt)
{
    __shared__ float tile[32][65];
    const int nt = (int)(VOXCH / 64);          // 4096 tiles per batch
    const int blk = blockIdx.x;
    const int b  = blk / nt;
    const int v0 = (blk - b * nt) * 64;
    const int t  = threadIdx.x;
    {
        const int c = t >> 3;                  // 0..31
        const int i = (t & 7) * 8;             // 0..56
        const float* src = vox + ((size_t)(b * Cn + c)) * VOXCH + v0 + i;
        const float4 a0 = *(const float4*)src;
        const float4 a1 = *(const float4*)(src + 4);
        tile[c][i + 0] = a0.x; tile[c][i + 1] = a0.y;
        tile[c][i + 2] = a0.z; tile[c][i + 3] = a0.w;
        tile[c][i + 4] = a1.x; tile[c][i + 5] = a1.y;
        tile[c][i + 6] = a1.z; tile[c][i + 7] = a1.w;
    }
    __syncthreads();
    {
        const int v  = t >> 2;                 // 0..63
        const int c8 = (t & 3) * 8;            // 0,8,16,24
        const unsigned p0 = pk2h(tile[c8 + 0][v], tile[c8 + 1][v]);
        const unsigned p1 = pk2h(tile[c8 + 2][v], tile[c8 + 3][v]);
        const unsigned p2 = pk2h(tile[c8 + 4][v], tile[c8 + 5][v]);
        const unsigned p3 = pk2h(tile[c8 + 6][v], tile[c8 + 7][v]);
        __half* dst = voxt + ((size_t)b * VOXCH + v0 + v) * Cn + c8;
        *(uint4*)dst = make_uint4(p0, p1, p2, p3);
    }
}

// ---------------- main: barrier-free phase-split fp16 sample ----------------
static constexpr int NBLK2 = Bn * ZS * XY;     // 18432 blocks (one (b,z,h) row)
static constexpr int CH2   = NBLK2 / 8;        // 2304 per XCD

__global__ __launch_bounds__(192) void sample_cl(
    const __half* __restrict__ voxt,
    const float* __restrict__ coef,
    float* __restrict__ out)
{
    __shared__ __align__(16) int   soff[3][32][8];   // per-wave corner byte offs
    __shared__ __align__(16) float swt[3][32][8];    // per-wave combined weights
    __shared__ float tr[3][32][34];                  // per-wave [w][c] out tile

    // bijective XCD-chunk swizzle (18432 % 8 == 0)
    const int logical = (blockIdx.x % 8) * CH2 + blockIdx.x / 8;
    const int b   = logical / (ZS * XY);
    const int rem = logical - b * (ZS * XY);
    const int z   = rem / XY;
    const int h   = rem - z * XY;

    const int t    = threadIdx.x;
    const int wave = t >> 6;                   // 0..2 -> w-tile of 32
    const int lane = t & 63;
    const int w0   = wave * 32;

    const float* C = coef + b * 16;            // uniform -> scalar loads

    // ---- phase 1 (per-wave): lanes 0..31 compute one sample each ----
    if (lane < 32) {
        const int w = w0 + lane;
        const float S100 = (96.0f / 95.0f) * 0.01f;
        const float u  = fmaf((float)w, S100, C[12]);
        const float v  = fmaf((float)h, S100, C[13]);
        const float Zt = fmaf((float)z, 1.0f / 47.0f, C[14]);

        const float ix = fmaf(fmaf(C[0], u, fmaf(C[1], v, C[2])), Zt, C[3]);
        const float iy = fmaf(fmaf(C[4], u, fmaf(C[5], v, C[6])), Zt, C[7]);
        const float iz = fmaf(fmaf(C[8], u, fmaf(C[9], v, C[10])), Zt, C[11]);

        const float fxf = floorf(ix), fyf = floorf(iy), fzf = floorf(iz);
        const float fx = ix - fxf, fy = iy - fyf, fz = iz - fzf;
        const int x0 = (int)fxf, y0 = (int)fyf, z0 = (int)fzf;

        const float ax0 = (1.0f - fx) * ((x0 >= 0     && x0 < WV)     ? 1.0f : 0.0f);
        const float ax1 = fx          * ((x0 + 1 >= 0 && x0 + 1 < WV) ? 1.0f : 0.0f);
        const float ay0 = (1.0f - fy) * ((y0 >= 0     && y0 < HV)     ? 1.0f : 0.0f);
        const float ay1 = fy          * ((y0 + 1 >= 0 && y0 + 1 < HV) ? 1.0f : 0.0f);
        const float az0 = (1.0f - fz) * ((z0 >= 0     && z0 < DV)     ? 1.0f : 0.0f);
        const float az1 = fz          * ((z0 + 1 >= 0 && z0 + 1 < DV) ? 1.0f : 0.0f);

        const int xc0 = min(max(x0, 0), WV - 1), xc1 = min(max(x0 + 1, 0), WV - 1);
        const int yc0 = min(max(y0, 0), HV - 1), yc1 = min(max(y0 + 1, 0), HV - 1);
        const int zc0 = min(max(z0, 0), DV - 1), zc1 = min(max(z0 + 1, 0), DV - 1);

        const int r00 = (zc0 * HV + yc0) * WV;
        const int r01 = (zc0 * HV + yc1) * WV;
        const int r10 = (zc1 * HV + yc0) * WV;
        const int r11 = (zc1 * HV + yc1) * WV;

        // byte offsets into f16 channels-last volume (voxel stride = 64 B)
        soff[wave][lane][0] = (r00 + xc0) << 6;
        soff[wave][lane][1] = (r00 + xc1) << 6;
        soff[wave][lane][2] = (r01 + xc0) << 6;
        soff[wave][lane][3] = (r01 + xc1) << 6;
        soff[wave][lane][4] = (r10 + xc0) << 6;
        soff[wave][lane][5] = (r10 + xc1) << 6;
        soff[wave][lane][6] = (r11 + xc0) << 6;
        soff[wave][lane][7] = (r11 + xc1) << 6;

        const float wz0y0 = az0 * ay0, wz0y1 = az0 * ay1;
        const float wz1y0 = az1 * ay0, wz1y1 = az1 * ay1;
        swt[wave][lane][0] = wz0y0 * ax0;
        swt[wave][lane][1] = wz0y0 * ax1;
        swt[wave][lane][2] = wz0y1 * ax0;
        swt[wave][lane][3] = wz0y1 * ax1;
        swt[wave][lane][4] = wz1y0 * ax0;
        swt[wave][lane][5] = wz1y0 * ax1;
        swt[wave][lane][6] = wz1y1 * ax0;
        swt[wave][lane][7] = wz1y1 * ax1;
    }
    // no barrier: soff/swt[wave] produced and consumed by the same wave

    // ---- phase 2: gather. 16 lanes per sample, 2 channels per lane ----
    const int sg = lane >> 4;                  // sample-in-quad 0..3
    const int li = lane & 15;                  // channel-pair index
    const int lb = li * 4;                     // byte offset within 64B corner

    const char* vb = (const char*)voxt + (size_t)b * VOXCH * (Cn * 2);

#pragma unroll
    for (int i = 0; i < 8; ++i) {
        const int sl = 4 * i + sg;             // sample within wave (0..31)
        const int4   o0 = *(const int4*)(&soff[wave][sl][0]);
        const int4   o1 = *(const int4*)(&soff[wave][sl][4]);
        const float4 wa = *(const float4*)(&swt[wave][sl][0]);
        const float4 wb = *(const float4*)(&swt[wave][sl][4]);

        const float2 f0 = __half22float2(*(const __half2*)(vb + (o0.x + lb)));
        const float2 f1 = __half22float2(*(const __half2*)(vb + (o0.y + lb)));
        const float2 f2 = __half22float2(*(const __half2*)(vb + (o0.z + lb)));
        const float2 f3 = __half22float2(*(const __half2*)(vb + (o0.w + lb)));
        const float2 f4 = __half22float2(*(const __half2*)(vb + (o1.x + lb)));
        const float2 f5 = __half22float2(*(const __half2*)(vb + (o1.y + lb)));
        const float2 f6 = __half22float2(*(const __half2*)(vb + (o1.z + lb)));
        const float2 f7 = __half22float2(*(const __half2*)(vb + (o1.w + lb)));

        float acc0 = wa.x * f0.x;
        float acc1 = wa.x * f0.y;
        acc0 = fmaf(wa.y, f1.x, acc0); acc1 = fmaf(wa.y, f1.y, acc1);
        acc0 = fmaf(wa.z, f2.x, acc0); acc1 = fmaf(wa.z, f2.y, acc1);
        acc0 = fmaf(wa.w, f3.x, acc0); acc1 = fmaf(wa.w, f3.y, acc1);
        acc0 = fmaf(wb.x, f4.x, acc0); acc1 = fmaf(wb.x, f4.y, acc1);
        acc0 = fmaf(wb.y, f5.x, acc0); acc1 = fmaf(wb.y, f5.y, acc1);
        acc0 = fmaf(wb.z, f6.x, acc0); acc1 = fmaf(wb.z, f6.y, acc1);
        acc0 = fmaf(wb.w, f7.x, acc0); acc1 = fmaf(wb.w, f7.y, acc1);

        *(float2*)(&tr[wave][sl][li * 2]) = make_float2(acc0, acc1);
    }
    // no barrier: tr[wave] read below by the same wave

    // ---- store: 8 lanes = one 128B channel row, f32x4 per lane ----
    const size_t orow = (size_t)b * Cn * SP + (size_t)(z * XY + h) * XY + w0;
    const int cb = lane >> 3;                  // channel within octet (0..7)
    const int wq = (lane & 7) * 4;             // w-quad start (0..28)
#pragma unroll
    for (int c2 = 0; c2 < 4; ++c2) {
        const int cc = c2 * 8 + cb;
        f32x4 v;
        v.x = tr[wave][wq + 0][cc];
        v.y = tr[wave][wq + 1][cc];
        v.z = tr[wave][wq + 2][cc];
        v.w = tr[wave][wq + 3][cc];
        __builtin_nontemporal_store(v, (f32x4*)(out + orow + (size_t)cc * SP + wq));
    }
}

// ---------------- fallback (round-2 kernel) if ws too small ----------------
static constexpr int TW = 32, TH = 4, TZ = 2;
static constexpr int NBW = XY / TW, NBH = XY / TH, NBZ = ZS / TZ;
static constexpr int BLOCKS_PER_B = NBW * NBH * NBZ;
static constexpr int NBLOCKS = Bn * BLOCKS_PER_B;
static constexpr int CHUNK = NBLOCKS / 8;

__global__ __launch_bounds__(256) void persp3d_fallback(
    const float* __restrict__ vox, const float* __restrict__ rot,
    const float* __restrict__ tran, const float* __restrict__ sc,
    const float* __restrict__ det, float* __restrict__ out)
{
    const int xcd = blockIdx.x % 8;
    const int logical = xcd * CHUNK + blockIdx.x / 8;
    const int b = logical / BLOCKS_PER_B;
    int rem = logical - b * BLOCKS_PER_B;
    const int bz = rem / (NBH * NBW);
    rem -= bz * (NBH * NBW);
    const int bh = rem / NBW;
    const int bw = rem - bh * NBW;
    const int t = threadIdx.x;
    const int w = bw * TW + (t & (TW - 1));
    const int h = bh * TH + ((t >> 5) & (TH - 1));
    const int z = bz * TZ + (t >> 7);
    const int sp = (z * XY + h) * XY + w;

    const float* R = rot + b * 16;
    const float* T = tran + b * 3;
    const float* S = sc + b * 3;
    const float* DT = det + b * 2;
    const float t0 = T[0], t1 = T[1], t2 = T[2];
    float M[3][4];
#pragma unroll
    for (int i = 0; i < 3; ++i) {
        const float inv = 1.0f / S[i];
        const float m0 = R[0 * 4 + i], m1 = R[1 * 4 + i], m2 = R[2 * 4 + i];
        M[i][0] = inv * m0; M[i][1] = inv * m1; M[i][2] = inv * m2;
        M[i][3] = -inv * (m0 * t0 + m1 * t1 + m2 * t2);
    }
    const float STEP = 96.0f / 95.0f;
    const float Zt = -0.5f + z * (1.0f / 47.0f) + t2;
    const float Xt = (w * STEP - 48.0f + DT[0]) * Zt * 0.01f;
    const float Yt = (h * STEP - 48.0f + DT[1]) * Zt * 0.01f;
    const float gx = 2.0f * (M[0][0] * Xt + M[0][1] * Yt + M[0][2] * Zt + M[0][3]);
    const float gy = 2.0f * (M[1][0] * Xt + M[1][1] * Yt + M[1][2] * Zt + M[1][3]);
    const float gz = 2.0f * (M[2][0] * Xt + M[2][1] * Yt + M[2][2] * Zt + M[2][3]);
    const float ix = (gx + 1.0f) * 31.5f, iy = (gy + 1.0f) * 31.5f, iz = (gz + 1.0f) * 31.5f;
    const float fx0 = floorf(ix), fy0 = floorf(iy), fz0 = floorf(iz);
    const float fx = ix - fx0, fy = iy - fy0, fz = iz - fz0;
    const int x0 = (int)fx0, y0 = (int)fy0, z0 = (int)fz0;
    const float ax0 = (1.0f - fx) * ((x0 >= 0 && x0 < WV) ? 1.0f : 0.0f);
    const float ax1 = fx * ((x0 + 1 >= 0 && x0 + 1 < WV) ? 1.0f : 0.0f);
    const float ay0 = (1.0f - fy) * ((y0 >= 0 && y0 < HV) ? 1.0f : 0.0f);
    const float ay1 = fy * ((y0 + 1 >= 0 && y0 + 1 < HV) ? 1.0f : 0.0f);
    const float az0 = (1.0f - fz) * ((z0 >= 0 && z0 < DV) ? 1.0f : 0.0f);
    const float az1 = fz * ((z0 + 1 >= 0 && z0 + 1 < DV) ? 1.0f : 0.0f);
    const int xc0 = min(max(x0, 0), WV - 1), xc1 = min(max(x0 + 1, 0), WV - 1);
    const int yc0 = min(max(y0, 0), HV - 1), yc1 = min(max(y0 + 1, 0), HV - 1);
    const int zc0 = min(max(z0, 0), DV - 1), zc1 = min(max(z0 + 1, 0), DV - 1);
    const int o000 = (zc0 * HV + yc0) * WV + xc0, o001 = (zc0 * HV + yc0) * WV + xc1;
    const int o010 = (zc0 * HV + yc1) * WV + xc0, o011 = (zc0 * HV + yc1) * WV + xc1;
    const int o100 = (zc1 * HV + yc0) * WV + xc0, o101 = (zc1 * HV + yc0) * WV + xc1;
    const int o110 = (zc1 * HV + yc1) * WV + xc0, o111 = (zc1 * HV + yc1) * WV + xc1;
    const float* p = vox + (size_t)b * Cn * VOXCH;
    float* op = out + (size_t)b * Cn * SP + sp;
#pragma unroll 8
    for (int cc = 0; cc < Cn; ++cc) {
        const float v000 = p[o000], v001 = p[o001];
        const float v010 = p[o010], v011 = p[o011];
        const float v100 = p[o100], v101 = p[o101];
        const float v110 = p[o110], v111 = p[o111];
        const float q00 = ax0 * v000 + ax1 * v001;
        const float q01 = ax0 * v010 + ax1 * v011;
        const float q10 = ax0 * v100 + ax1 * v101;
        const float q11 = ax0 * v110 + ax1 * v111;
        const float r0 = ay0 * q00 + ay1 * q01;
        const float r1 = ay0 * q10 + ay1 * q11;
        __builtin_nontemporal_store(az0 * r0 + az1 * r1, op);
        p += VOXCH; op += SP;
    }
}

extern "C" void kernel_launch(void* const* d_in, const int* in_sizes, int n_in,
                              void* d_out, int out_size, void* d_ws, size_t ws_size,
                              hipStream_t stream) {
    const float* vox  = (const float*)d_in[0];
    const float* rot  = (const float*)d_in[1];
    const float* tran = (const float*)d_in[2];
    const float* sc   = (const float*)d_in[3];
    const float* det  = (const float*)d_in[4];
    float* out = (float*)d_out;

    if (ws_size >= WS_NEED) {
        __half* voxt = (__half*)d_ws;
        float* coef  = (float*)((char*)d_ws + VOXT_BYTES);
        setup_coefs<<<dim3(1), dim3(64), 0, stream>>>(rot, tran, sc, det, coef);
        transpose_cl<<<dim3(Bn * (int)(VOXCH / 64)), dim3(256), 0, stream>>>(vox, voxt);
        sample_cl<<<dim3(NBLK2), dim3(192), 0, stream>>>(voxt, coef, out);
    } else {
        persp3d_fallback<<<dim3(NBLOCKS), dim3(256), 0, stream>>>(vox, rot, tran, sc, det, out);
    }
}